// Round 2
// baseline (346.359 us; speedup 1.0000x reference)
//
#include <hip/hip_runtime.h>

typedef unsigned short u16;
typedef unsigned int u32;
typedef __attribute__((ext_vector_type(8))) short bf16x8;
typedef __attribute__((ext_vector_type(4))) float f32x4;

#define LOG2E 1.4426950408889634f

__device__ __forceinline__ u16 f2bf(float f) {
    u32 u = __float_as_uint(f);
    u += 0x7fffu + ((u >> 16) & 1u);
    return (u16)(u >> 16);
}
__device__ __forceinline__ float bf2f(u16 s) {
    return __uint_as_float(((u32)s) << 16);
}

// ---------------- Kernel 0: weight conversion fp32 -> bf16 ----------------
// wbf layout: [0]=Wq [1]=Wk [2]=Wv [3]=Wg [4]=Wo, each 128x128 row-major (n,k)
__global__ void wconv_kernel(const float* __restrict__ Wq, const float* __restrict__ Wk,
                             const float* __restrict__ Wv, const float* __restrict__ Wg,
                             const float* __restrict__ Wo, u16* __restrict__ wbf) {
    int idx = blockIdx.x * blockDim.x + threadIdx.x;  // 0..16383
    wbf[0 * 16384 + idx] = f2bf(Wq[idx]);
    wbf[1 * 16384 + idx] = f2bf(Wk[idx]);
    wbf[2 * 16384 + idx] = f2bf(Wv[idx]);
    wbf[3 * 16384 + idx] = f2bf(Wg[idx]);
    wbf[4 * 16384 + idx] = f2bf(Wo[idx]);
}

// ---------------- Kernel 1: fused LN + QKVG projection + attention ----------------
// One block per (pair-row l, head h). 256 threads = 4 waves. 1 block/CU (LDS-bound).
__global__ __launch_bounds__(256, 1)
void attn_kernel(const float* __restrict__ pair,
                 const float* __restrict__ norm_w,
                 const float* __restrict__ norm_b,
                 const float* __restrict__ bg,
                 const float* __restrict__ Wb,
                 const u16* __restrict__ wbf,
                 u16* __restrict__ Obf) {
    const int l = blockIdx.x >> 2;
    const int h = blockIdx.x & 3;
    const int tid = threadIdx.x;
    const int wave = tid >> 6;
    const int lane = tid & 63;
    const int i_lo = lane & 15;
    const int q = lane >> 4;

    // LDS: ~115 KB total
    __shared__ __align__(16) u16 Xs[64 * 136];    // LN'd x tile (64 rows x 128, pad->136)
    __shared__ __align__(16) u16 Qs[320 * 40];    // Q[j][d], pad 32->40
    __shared__ __align__(16) u16 Ks[320 * 40];    // K[j][d]
    __shared__ __align__(16) u16 Gs[320 * 40];    // sigmoid gate g[i][d]
    __shared__ __align__(16) u16 VTs[32 * 328];   // V^T[d][j], pad 320->328
    __shared__ __align__(16) float biasLds[320];  // bias[j] * log2e
    __shared__ __align__(16) float wls[3 * 128];  // norm_w | norm_b | Wb[h]  (NO padding:
                                                  // Round-1 pad formula overflowed sections -> LDS corruption)

    // stage LN weights + Wb[h] into LDS
    if (tid < 96) {
        int a = tid >> 5;
        int t = tid & 31;
        const float* src = (a == 0) ? norm_w : (a == 1) ? norm_b : (Wb + h * 128);
        f32x4 v = *(const f32x4*)(src + t * 4);
        *(f32x4*)&wls[a * 128 + t * 4] = v;
    }

    // per-lane gate bias (cols h*32 + {i_lo, 16+i_lo})
    float bg0 = bg[h * 32 + i_lo];
    float bg1 = bg[h * 32 + 16 + i_lo];

    // Hoist weight B-fragments for the whole block (L2-resident; 128 VGPRs).
    // nt: 0,1=Q  2,3=K  4,5=V  6,7=G.  B[k][n] = W[n][k] (native row layout).
    bf16x8 wfrag[4][8];
#pragma unroll
    for (int kc = 0; kc < 4; ++kc)
#pragma unroll
        for (int nt = 0; nt < 8; ++nt) {
            int mat = nt >> 1;
            int drow = h * 32 + (nt & 1) * 16 + i_lo;
            wfrag[kc][nt] = *(const bf16x8*)&wbf[mat * 16384 + drow * 128 + kc * 32 + q * 8];
        }

    __syncthreads();  // wls visible

    const int row_g = tid >> 2;  // 0..63: local row in 64-row tile
    const int c4 = tid & 3;      // 32-col quarter

    // ---------- Phase A: LN + projections, 5 tiles of 64 rows ----------
#pragma unroll 1
    for (int jt5 = 0; jt5 < 5; ++jt5) {
        int j0 = jt5 * 64;
        const float* prow = pair + ((size_t)(l * 320 + j0 + row_g)) * 128 + c4 * 32;
        f32x4 pr[8];
#pragma unroll
        for (int u = 0; u < 8; ++u) pr[u] = *(const f32x4*)(prow + u * 4);

        float s = 0.f, s2 = 0.f, bd = 0.f;
#pragma unroll
        for (int u = 0; u < 8; ++u) {
            f32x4 p = pr[u];
            f32x4 wb4 = *(const f32x4*)&wls[2 * 128 + c4 * 32 + u * 4];
            s += p[0] + p[1] + p[2] + p[3];
            s2 += p[0] * p[0] + p[1] * p[1] + p[2] * p[2] + p[3] * p[3];
            bd += p[0] * wb4[0] + p[1] * wb4[1] + p[2] * wb4[2] + p[3] * wb4[3];
        }
        s += __shfl_xor(s, 1);   s += __shfl_xor(s, 2);
        s2 += __shfl_xor(s2, 1); s2 += __shfl_xor(s2, 2);
        bd += __shfl_xor(bd, 1); bd += __shfl_xor(bd, 2);
        float mu = s * 0.0078125f;
        float var = s2 * 0.0078125f - mu * mu;
        float rs = rsqrtf(var + 1e-5f);

        __syncthreads();  // previous tile's Xs reads are done
#pragma unroll
        for (int u = 0; u < 8; ++u) {
            f32x4 p = pr[u];
            f32x4 w4 = *(const f32x4*)&wls[0 * 128 + c4 * 32 + u * 4];
            f32x4 b4 = *(const f32x4*)&wls[1 * 128 + c4 * 32 + u * 4];
            ushort4 xv;
            xv.x = f2bf((p[0] - mu) * rs * w4[0] + b4[0]);
            xv.y = f2bf((p[1] - mu) * rs * w4[1] + b4[1]);
            xv.z = f2bf((p[2] - mu) * rs * w4[2] + b4[2]);
            xv.w = f2bf((p[3] - mu) * rs * w4[3] + b4[3]);
            *(ushort4*)&Xs[row_g * 136 + c4 * 32 + u * 4] = xv;
        }
        if (c4 == 0) biasLds[j0 + row_g] = bd * LOG2E;  // raw-pair bias, log2e folded
        __syncthreads();

        // X(64x128) @ [Wq|Wk|Wv|Wg]_h^T (128x128); wave handles rows [wave*16, wave*16+16)
        f32x4 acc[8];
#pragma unroll
        for (int nt = 0; nt < 8; ++nt) acc[nt] = (f32x4){0.f, 0.f, 0.f, 0.f};
#pragma unroll
        for (int kc = 0; kc < 4; ++kc) {
            bf16x8 a = *(const bf16x8*)&Xs[(wave * 16 + i_lo) * 136 + kc * 32 + q * 8];
#pragma unroll
            for (int nt = 0; nt < 8; ++nt)
                acc[nt] = __builtin_amdgcn_mfma_f32_16x16x32_bf16(a, wfrag[kc][nt], acc[nt], 0, 0, 0);
        }
        // epilogue: C/D layout row=(q*4+r), col=i_lo -> scatter to LDS tiles
        int jrow = j0 + wave * 16 + q * 4;
#pragma unroll
        for (int nt = 0; nt < 8; ++nt) {
#pragma unroll
            for (int r = 0; r < 4; ++r) {
                float v = acc[nt][r];
                int jr = jrow + r;
                int dl = (nt & 1) * 16 + i_lo;
                if (nt < 2)      Qs[jr * 40 + dl] = f2bf(v);
                else if (nt < 4) Ks[jr * 40 + dl] = f2bf(v);
                else if (nt < 6) VTs[dl * 328 + jr] = f2bf(v);
                else {
                    float z = v + ((nt & 1) ? bg1 : bg0);
                    float g = 1.0f / (1.0f + exp2f(-z * LOG2E));
                    Gs[jr * 40 + dl] = f2bf(g);
                }
            }
        }
    }
    __syncthreads();  // Q/K/VT/G/bias all visible

    // ---------- Phase B: attention. Wave w owns i in [w*80, w*80+80), 5 strips of 16 ----------
    const float SC = 0.17677669529663687f * LOG2E;  // Dh^-0.5 * log2e
    const f32x4 zero4 = {0.f, 0.f, 0.f, 0.f};
#pragma unroll 1
    for (int s5 = 0; s5 < 5; ++s5) {
        int i0 = wave * 80 + s5 * 16;
        // B-frag: Q[i][d], n=i=lane&15, k=d=q*8+jj
        bf16x8 qf = *(const bf16x8*)&Qs[(i0 + i_lo) * 40 + q * 8];

        // S^T = K * Q^T: lane holds S[i=i_lo][j = jt*16 + q*4 + r]
        f32x4 sc[20];
#pragma unroll
        for (int jt = 0; jt < 20; ++jt) {
            bf16x8 kf = *(const bf16x8*)&Ks[(jt * 16 + i_lo) * 40 + q * 8];
            sc[jt] = __builtin_amdgcn_mfma_f32_16x16x32_bf16(kf, qf, zero4, 0, 0, 0);
        }
        // scale + bias (broadcast b128 per quad), track max
        float mx = -3.0e38f;
#pragma unroll
        for (int jt = 0; jt < 20; ++jt) {
            f32x4 b4 = *(const f32x4*)&biasLds[jt * 16 + q * 4];
#pragma unroll
            for (int r = 0; r < 4; ++r) {
                float v = sc[jt][r] * SC + b4[r];
                sc[jt][r] = v;
                mx = fmaxf(mx, v);
            }
        }
        mx = fmaxf(mx, __shfl_xor(mx, 16));
        mx = fmaxf(mx, __shfl_xor(mx, 32));
        float sum = 0.f;
#pragma unroll
        for (int jt = 0; jt < 20; ++jt)
#pragma unroll
            for (int r = 0; r < 4; ++r) {
                float p = exp2f(sc[jt][r] - mx);
                sc[jt][r] = p;
                sum += p;
            }
        sum += __shfl_xor(sum, 16);
        sum += __shfl_xor(sum, 32);
        float rinv = 1.0f / sum;

        // O^T = V^T * P: P fragment built by cross-lane shfl transpose of sc
        f32x4 oacc[2];
        oacc[0] = zero4; oacc[1] = zero4;
        const int srcb = ((q & 1) * 2) * 16 + i_lo;
        const bool hiq = (q >= 2);
#pragma unroll
        for (int kt = 0; kt < 10; ++kt) {
            union { bf16x8 v; u16 u[8]; } pu;
#pragma unroll
            for (int jj = 0; jj < 8; ++jj) {
                int r = jj & 3;
                int src = srcb + ((jj >> 2) << 4);
                float lo = __shfl(sc[2 * kt][r], src, 64);
                float hi = __shfl(sc[2 * kt + 1][r], src, 64);
                pu.u[jj] = f2bf(hiq ? hi : lo);
            }
#pragma unroll
            for (int mt = 0; mt < 2; ++mt) {
                bf16x8 vf = *(const bf16x8*)&VTs[(mt * 16 + i_lo) * 328 + kt * 32 + q * 8];
                oacc[mt] = __builtin_amdgcn_mfma_f32_16x16x32_bf16(vf, pu.v, oacc[mt], 0, 0, 0);
            }
        }
        // epilogue: O^T lane holds (d = mt*16+q*4+r, i = i_lo); gate, normalize, store bf16
#pragma unroll
        for (int mt = 0; mt < 2; ++mt)
#pragma unroll
            for (int r = 0; r < 4; ++r) {
                int d = mt * 16 + q * 4 + r;
                float g = bf2f(Gs[(i0 + i_lo) * 40 + d]);
                float o = oacc[mt][r] * rinv * g;
                Obf[((size_t)(l * 320 + i0 + i_lo)) * 128 + h * 32 + d] = f2bf(o);
            }
    }
}

// ---------------- Kernel 2: out = pair + O @ Wo^T + bo ----------------
__global__ __launch_bounds__(256)
void outproj_kernel(const float* __restrict__ pair,
                    const float* __restrict__ bo,
                    const u16* __restrict__ Obf,
                    const u16* __restrict__ wbf,
                    float* __restrict__ out) {
    const int tid = threadIdx.x;
    const int wave = tid >> 6;
    const int lane = tid & 63;
    const int i_lo = lane & 15;
    const int q = lane >> 4;
    const int mrow = blockIdx.x * 64 + wave * 16;
    const u16* Wo = wbf + 4 * 16384;

    bf16x8 of[4];
#pragma unroll
    for (int kc = 0; kc < 4; ++kc)
        of[kc] = *(const bf16x8*)&Obf[((size_t)(mrow + i_lo)) * 128 + kc * 32 + q * 8];

    float bov[8];
#pragma unroll
    for (int nt = 0; nt < 8; ++nt) bov[nt] = bo[nt * 16 + i_lo];

    f32x4 acc[8];
#pragma unroll
    for (int nt = 0; nt < 8; ++nt) acc[nt] = (f32x4){0.f, 0.f, 0.f, 0.f};
#pragma unroll
    for (int nt = 0; nt < 8; ++nt) {
#pragma unroll
        for (int kc = 0; kc < 4; ++kc) {
            bf16x8 wf = *(const bf16x8*)&Wo[(nt * 16 + i_lo) * 128 + kc * 32 + q * 8];
            acc[nt] = __builtin_amdgcn_mfma_f32_16x16x32_bf16(of[kc], wf, acc[nt], 0, 0, 0);
        }
    }
#pragma unroll
    for (int nt = 0; nt < 8; ++nt)
#pragma unroll
        for (int r = 0; r < 4; ++r) {
            size_t idx = ((size_t)(mrow + q * 4 + r)) * 128 + nt * 16 + i_lo;
            out[idx] = acc[nt][r] + pair[idx] + bov[nt];
        }
}

extern "C" void kernel_launch(void* const* d_in, const int* in_sizes, int n_in,
                              void* d_out, int out_size, void* d_ws, size_t ws_size,
                              hipStream_t stream) {
    const float* pair   = (const float*)d_in[0];
    const float* norm_w = (const float*)d_in[1];
    const float* norm_b = (const float*)d_in[2];
    const float* Wq     = (const float*)d_in[3];
    const float* Wk     = (const float*)d_in[4];
    const float* Wv     = (const float*)d_in[5];
    const float* Wg     = (const float*)d_in[6];
    const float* bg     = (const float*)d_in[7];
    const float* Wo     = (const float*)d_in[8];
    const float* bo     = (const float*)d_in[9];
    const float* Wb     = (const float*)d_in[10];

    u16* wbf = (u16*)d_ws;       // 5 * 128*128 bf16 weights
    u16* Obf = wbf + 5 * 16384;  // 102400 x 128 bf16 gated attention output
    float* out = (float*)d_out;

    wconv_kernel<<<64, 256, 0, stream>>>(Wq, Wk, Wv, Wg, Wo, wbf);
    attn_kernel<<<320 * 4, 256, 0, stream>>>(pair, norm_w, norm_b, bg, Wb, wbf, Obf);
    outproj_kernel<<<1600, 256, 0, stream>>>(pair, bo, Obf, wbf, out);
}

// Round 3
// 291.000 us; speedup vs baseline: 1.1902x; 1.1902x over previous
//
#include <hip/hip_runtime.h>

typedef unsigned short u16;
typedef unsigned int u32;
typedef __attribute__((ext_vector_type(8))) short bf16x8;
typedef __attribute__((ext_vector_type(4))) float f32x4;
typedef __attribute__((ext_vector_type(2))) unsigned int u32x2;

#define LOG2E 1.4426950408889634f

__device__ __forceinline__ u16 f2bf(float f) {
    u32 u = __float_as_uint(f);
    u += 0x7fffu + ((u >> 16) & 1u);
    return (u16)(u >> 16);
}
__device__ __forceinline__ float bf2f(u16 s) {
    return __uint_as_float(((u32)s) << 16);
}
// pack two f32 -> two truncated bf16 in one v_perm (hi in bits 31:16, lo in 15:0)
__device__ __forceinline__ u32 pk_bf_trunc(float hi, float lo) {
    return __builtin_amdgcn_perm(__float_as_uint(hi), __float_as_uint(lo), 0x07060302u);
}

// ---------------- Kernel 0: weight conversion fp32 -> bf16 ----------------
__global__ void wconv_kernel(const float* __restrict__ Wq, const float* __restrict__ Wk,
                             const float* __restrict__ Wv, const float* __restrict__ Wg,
                             const float* __restrict__ Wo, u16* __restrict__ wbf) {
    int idx = blockIdx.x * blockDim.x + threadIdx.x;  // 0..16383
    wbf[0 * 16384 + idx] = f2bf(Wq[idx]);
    wbf[1 * 16384 + idx] = f2bf(Wk[idx]);
    wbf[2 * 16384 + idx] = f2bf(Wv[idx]);
    wbf[3 * 16384 + idx] = f2bf(Wg[idx]);
    wbf[4 * 16384 + idx] = f2bf(Wo[idx]);
}

// ---------------- Kernel 1: fused LN + QKVG projection + attention ----------------
// One block per (pair-row l, head h). 512 threads = 8 waves -> 2 waves/SIMD at 1 block/CU.
// smem u16 layout:
//   [0, 21504)        : Phase A Xs (128x136) ALIASED with Phase B per-wave P-buffers (8 x 16x168)
//   [21504, 34304)    : Qs 320x40
//   [34304, 47104)    : Ks 320x40
//   [47104, 59904)    : Gs 320x40
//   [59904, 70400)    : VTs 32x328
#define PBUF_W 2688   // 16*168 u16 per wave
#define QS_OFF 21504
#define KS_OFF 34304
#define GS_OFF 47104
#define VTS_OFF 59904

__global__ __launch_bounds__(512, 2)
void attn_kernel(const float* __restrict__ pair,
                 const float* __restrict__ norm_w,
                 const float* __restrict__ norm_b,
                 const float* __restrict__ bg,
                 const float* __restrict__ Wb,
                 const u16* __restrict__ wbf,
                 u16* __restrict__ Obf) {
    const int l = blockIdx.x >> 2;
    const int h = blockIdx.x & 3;
    const int tid = threadIdx.x;
    const int wave = tid >> 6;
    const int lane = tid & 63;
    const int i_lo = lane & 15;
    const int q = lane >> 4;

    __shared__ __align__(16) u16 smem[70400];
    __shared__ __align__(16) float biasLds[320];  // bias[j] * log2e
    __shared__ __align__(16) float wls[3 * 128];  // norm_w | norm_b | Wb[h]

    if (tid < 96) {
        int a = tid >> 5;
        int t = tid & 31;
        const float* src = (a == 0) ? norm_w : (a == 1) ? norm_b : (Wb + h * 128);
        f32x4 v = *(const f32x4*)(src + t * 4);
        *(f32x4*)&wls[a * 128 + t * 4] = v;
    }

    float bg0 = bg[h * 32 + i_lo];
    float bg1 = bg[h * 32 + 16 + i_lo];

    // Hoisted weight B-fragments (L2-resident). nt: 0,1=Q 2,3=K 4,5=V 6,7=G.
    bf16x8 wfrag[4][8];
#pragma unroll
    for (int kc = 0; kc < 4; ++kc)
#pragma unroll
        for (int nt = 0; nt < 8; ++nt) {
            int mat = nt >> 1;
            int drow = h * 32 + (nt & 1) * 16 + i_lo;
            wfrag[kc][nt] = *(const bf16x8*)&wbf[mat * 16384 + drow * 128 + kc * 32 + q * 8];
        }

    __syncthreads();  // wls visible

    const int row_g = tid >> 2;  // 0..127
    const int c4 = tid & 3;

    // ---------- Phase A: LN + projections. Tiles: 128,128,64 rows ----------
#pragma unroll 1
    for (int t = 0; t < 3; ++t) {
        const int j0 = t * 128;
        const int nrows = (t == 2) ? 64 : 128;
        const bool act = row_g < nrows;

        f32x4 pr[8];
        float mu, rs, bd;
        if (act) {
            const float* prow = pair + ((size_t)(l * 320 + j0 + row_g)) * 128 + c4 * 32;
#pragma unroll
            for (int u = 0; u < 8; ++u) pr[u] = *(const f32x4*)(prow + u * 4);
            float s = 0.f, s2 = 0.f;
            bd = 0.f;
#pragma unroll
            for (int u = 0; u < 8; ++u) {
                f32x4 p = pr[u];
                f32x4 wb4 = *(const f32x4*)&wls[2 * 128 + c4 * 32 + u * 4];
                s += p[0] + p[1] + p[2] + p[3];
                s2 += p[0] * p[0] + p[1] * p[1] + p[2] * p[2] + p[3] * p[3];
                bd += p[0] * wb4[0] + p[1] * wb4[1] + p[2] * wb4[2] + p[3] * wb4[3];
            }
            s += __shfl_xor(s, 1);   s += __shfl_xor(s, 2);
            s2 += __shfl_xor(s2, 1); s2 += __shfl_xor(s2, 2);
            bd += __shfl_xor(bd, 1); bd += __shfl_xor(bd, 2);
            mu = s * 0.0078125f;
            float var = s2 * 0.0078125f - mu * mu;
            rs = rsqrtf(var + 1e-5f);
        }

        __syncthreads();  // previous tile's Xs reads done
        if (act) {
#pragma unroll
            for (int u = 0; u < 8; ++u) {
                f32x4 p = pr[u];
                f32x4 w4 = *(const f32x4*)&wls[0 * 128 + c4 * 32 + u * 4];
                f32x4 b4 = *(const f32x4*)&wls[1 * 128 + c4 * 32 + u * 4];
                ushort4 xv;
                xv.x = f2bf((p[0] - mu) * rs * w4[0] + b4[0]);
                xv.y = f2bf((p[1] - mu) * rs * w4[1] + b4[1]);
                xv.z = f2bf((p[2] - mu) * rs * w4[2] + b4[2]);
                xv.w = f2bf((p[3] - mu) * rs * w4[3] + b4[3]);
                *(ushort4*)&smem[row_g * 136 + c4 * 32 + u * 4] = xv;
            }
            if (c4 == 0) biasLds[j0 + row_g] = bd * LOG2E;
        }
        __syncthreads();

        if (wave * 16 < nrows) {
            f32x4 acc[8];
#pragma unroll
            for (int nt = 0; nt < 8; ++nt) acc[nt] = (f32x4){0.f, 0.f, 0.f, 0.f};
#pragma unroll
            for (int kc = 0; kc < 4; ++kc) {
                bf16x8 a = *(const bf16x8*)&smem[(wave * 16 + i_lo) * 136 + kc * 32 + q * 8];
#pragma unroll
                for (int nt = 0; nt < 8; ++nt)
                    acc[nt] = __builtin_amdgcn_mfma_f32_16x16x32_bf16(a, wfrag[kc][nt], acc[nt], 0, 0, 0);
            }
            int jrow = j0 + wave * 16 + q * 4;
#pragma unroll
            for (int nt = 0; nt < 8; ++nt) {
#pragma unroll
                for (int r = 0; r < 4; ++r) {
                    float v = acc[nt][r];
                    int jr = jrow + r;
                    int dl = (nt & 1) * 16 + i_lo;
                    if (nt < 2)      smem[QS_OFF + jr * 40 + dl] = f2bf(v);
                    else if (nt < 4) smem[KS_OFF + jr * 40 + dl] = f2bf(v);
                    else if (nt < 6) smem[VTS_OFF + dl * 328 + jr] = f2bf(v);
                    else {
                        float z = v + ((nt & 1) ? bg1 : bg0);
                        float g = 1.0f / (1.0f + exp2f(-z * LOG2E));
                        smem[GS_OFF + jr * 40 + dl] = f2bf(g);
                    }
                }
            }
        }
    }
    __syncthreads();  // Q/K/VT/G/bias visible; Xs region free for P-buffers

    // ---------- Phase B: attention. 20 strips round-robin over 8 waves ----------
    const float SC = 0.17677669529663687f * LOG2E;
    const f32x4 zero4 = {0.f, 0.f, 0.f, 0.f};
    u16* pb = smem + wave * PBUF_W;  // per-wave 16x168 P transpose buffer
#pragma unroll 1
    for (int t2 = 0; t2 < 3; ++t2) {
        const int strip = wave + 8 * t2;
        if (strip >= 20) break;
        const int i0 = strip * 16;
        bf16x8 qf = *(const bf16x8*)&smem[QS_OFF + (i0 + i_lo) * 40 + q * 8];

        // S^T = K * Q^T: lane holds S[i=i_lo][j = jt*16 + q*4 + r]
        f32x4 sc[20];
#pragma unroll
        for (int jt = 0; jt < 20; ++jt) {
            bf16x8 kf = *(const bf16x8*)&smem[KS_OFF + (jt * 16 + i_lo) * 40 + q * 8];
            sc[jt] = __builtin_amdgcn_mfma_f32_16x16x32_bf16(kf, qf, zero4, 0, 0, 0);
        }
        // p = exp2(s*SC + bias); no max subtraction (|arg| < ~15, fp32-safe)
        float sum = 0.f;
#pragma unroll
        for (int jt = 0; jt < 20; ++jt) {
            f32x4 b4 = *(const f32x4*)&biasLds[jt * 16 + q * 4];
#pragma unroll
            for (int r = 0; r < 4; ++r) {
                float p = exp2f(sc[jt][r] * SC + b4[r]);
                sc[jt][r] = p;
                sum += p;
            }
        }
        sum += __shfl_xor(sum, 16);
        sum += __shfl_xor(sum, 32);
        float rinv = 1.0f / sum;

        // O^T = V^T * P^T-read: roundtrip P through per-wave LDS, two 160-j halves
        f32x4 oacc[2];
        oacc[0] = zero4; oacc[1] = zero4;
#pragma unroll
        for (int hh = 0; hh < 2; ++hh) {
#pragma unroll
            for (int jt10 = 0; jt10 < 10; ++jt10) {
                f32x4 s4 = sc[hh * 10 + jt10];
                u32x2 pk;
                pk.x = pk_bf_trunc(s4[1], s4[0]);
                pk.y = pk_bf_trunc(s4[3], s4[2]);
                *(u32x2*)&pb[i_lo * 168 + jt10 * 16 + q * 4] = pk;
            }
#pragma unroll
            for (int kt = 0; kt < 5; ++kt) {
                bf16x8 pf = *(const bf16x8*)&pb[i_lo * 168 + kt * 32 + q * 8];
#pragma unroll
                for (int mt = 0; mt < 2; ++mt) {
                    bf16x8 vf = *(const bf16x8*)&smem[VTS_OFF + (mt * 16 + i_lo) * 328 + hh * 160 + kt * 32 + q * 8];
                    oacc[mt] = __builtin_amdgcn_mfma_f32_16x16x32_bf16(vf, pf, oacc[mt], 0, 0, 0);
                }
            }
        }
        // epilogue: lane holds O^T[d = mt*16+q*4+r][i = i0+i_lo]; gate, normalize, pack 8B stores
#pragma unroll
        for (int mt = 0; mt < 2; ++mt) {
            ushort4 g4 = *(const ushort4*)&smem[GS_OFF + (i0 + i_lo) * 40 + mt * 16 + q * 4];
            float o0 = oacc[mt][0] * rinv * bf2f(g4.x);
            float o1 = oacc[mt][1] * rinv * bf2f(g4.y);
            float o2 = oacc[mt][2] * rinv * bf2f(g4.z);
            float o3 = oacc[mt][3] * rinv * bf2f(g4.w);
            u32x2 pk;
            pk.x = pk_bf_trunc(o1, o0);
            pk.y = pk_bf_trunc(o3, o2);
            *(u32x2*)&Obf[((size_t)(l * 320 + i0 + i_lo)) * 128 + h * 32 + mt * 16 + q * 4] = pk;
        }
    }
}

// ---------------- Kernel 2: out = pair + O @ Wo^T + bo ----------------
// Computes (Wo * O^T): C-layout gives 4 consecutive out-columns per lane -> f32x4 I/O.
__global__ __launch_bounds__(256)
void outproj_kernel(const float* __restrict__ pair,
                    const float* __restrict__ bo,
                    const u16* __restrict__ Obf,
                    const u16* __restrict__ wbf,
                    float* __restrict__ out) {
    const int tid = threadIdx.x;
    const int wave = tid >> 6;
    const int lane = tid & 63;
    const int i_lo = lane & 15;
    const int q = lane >> 4;
    const int mrow = blockIdx.x * 64 + wave * 16;
    const u16* Wo = wbf + 4 * 16384;

    bf16x8 of[4];
#pragma unroll
    for (int kc = 0; kc < 4; ++kc)
        of[kc] = *(const bf16x8*)&Obf[((size_t)(mrow + i_lo)) * 128 + kc * 32 + q * 8];

    f32x4 acc[8];
#pragma unroll
    for (int nt = 0; nt < 8; ++nt) acc[nt] = (f32x4){0.f, 0.f, 0.f, 0.f};
#pragma unroll
    for (int nt = 0; nt < 8; ++nt) {
#pragma unroll
        for (int kc = 0; kc < 4; ++kc) {
            bf16x8 wf = *(const bf16x8*)&Wo[(nt * 16 + i_lo) * 128 + kc * 32 + q * 8];
            acc[nt] = __builtin_amdgcn_mfma_f32_16x16x32_bf16(wf, of[kc], acc[nt], 0, 0, 0);
        }
    }
    // lane holds out[row = mrow+i_lo][col = nt*16 + q*4 + r] -> f32x4
#pragma unroll
    for (int nt = 0; nt < 8; ++nt) {
        size_t idx = ((size_t)(mrow + i_lo)) * 128 + nt * 16 + q * 4;
        f32x4 p4 = *(const f32x4*)&pair[idx];
        f32x4 b4 = *(const f32x4*)&bo[nt * 16 + q * 4];
        f32x4 o4;
        o4[0] = acc[nt][0] + p4[0] + b4[0];
        o4[1] = acc[nt][1] + p4[1] + b4[1];
        o4[2] = acc[nt][2] + p4[2] + b4[2];
        o4[3] = acc[nt][3] + p4[3] + b4[3];
        *(f32x4*)&out[idx] = o4;
    }
}

extern "C" void kernel_launch(void* const* d_in, const int* in_sizes, int n_in,
                              void* d_out, int out_size, void* d_ws, size_t ws_size,
                              hipStream_t stream) {
    const float* pair   = (const float*)d_in[0];
    const float* norm_w = (const float*)d_in[1];
    const float* norm_b = (const float*)d_in[2];
    const float* Wq     = (const float*)d_in[3];
    const float* Wk     = (const float*)d_in[4];
    const float* Wv     = (const float*)d_in[5];
    const float* Wg     = (const float*)d_in[6];
    const float* bg     = (const float*)d_in[7];
    const float* Wo     = (const float*)d_in[8];
    const float* bo     = (const float*)d_in[9];
    const float* Wb     = (const float*)d_in[10];

    u16* wbf = (u16*)d_ws;       // 5 * 128*128 bf16 weights
    u16* Obf = wbf + 5 * 16384;  // 102400 x 128 bf16 gated attention output
    float* out = (float*)d_out;

    wconv_kernel<<<64, 256, 0, stream>>>(Wq, Wk, Wv, Wg, Wo, wbf);
    attn_kernel<<<320 * 4, 512, 0, stream>>>(pair, norm_w, norm_b, bg, Wb, wbf, Obf);
    outproj_kernel<<<1600, 256, 0, stream>>>(pair, bo, Obf, wbf, out);
}